// Round 3
// baseline (749.162 us; speedup 1.0000x reference)
//
#include <hip/hip_runtime.h>
#include <stdint.h>

#define B_TOTAL 4096
#define T_STEPS 512
#define IN_DIM 16
#define H1 5
#define H2 50
#define NCLS 20

typedef __attribute__((ext_vector_type(8))) short bf16x8;
typedef __attribute__((ext_vector_type(4))) float f32x4;

#define LOG2E 1.44269504f
__device__ inline float sigm(float x){
  float e = __builtin_amdgcn_exp2f(-LOG2E * x);
  return __builtin_amdgcn_rcpf(1.0f + e);
}
__device__ inline float tanh_(float x){
  float e = __builtin_amdgcn_exp2f((2.0f*LOG2E) * x);
  float r = __builtin_amdgcn_rcpf(1.0f + e);
  return fmaf(-2.0f, r, 1.0f);
}
// dword = [top16(a) | top16(b)]  (memory shorts: [0]=b, [1]=a)
__device__ inline unsigned pack_top(float a, float b){
  return __builtin_amdgcn_perm(__float_as_uint(a), __float_as_uint(b), 0x07060302u);
}
// trunc split of float4 -> 4 hi shorts + 4 lo shorts (uint2 each)
__device__ inline void cvt_store(unsigned short* dh, unsigned short* dl, float4 v){
  unsigned x0=__float_as_uint(v.x), x1=__float_as_uint(v.y),
           x2=__float_as_uint(v.z), x3=__float_as_uint(v.w);
  uint2 H, L;
  H.x = pack_top(v.y, v.x);
  H.y = pack_top(v.w, v.z);
  float r0 = v.x - __uint_as_float(x0 & 0xFFFF0000u);
  float r1 = v.y - __uint_as_float(x1 & 0xFFFF0000u);
  float r2 = v.z - __uint_as_float(x2 & 0xFFFF0000u);
  float r3 = v.w - __uint_as_float(x3 & 0xFFFF0000u);
  L.x = pack_top(r1, r0);
  L.y = pack_top(r3, r2);
  *(uint2*)dh = H; *(uint2*)dl = L;
}
__device__ inline void split1(float h, unsigned short& hi, unsigned short& lo){
  unsigned u = __float_as_uint(h);
  hi = (unsigned short)(u >> 16);
  float r = h - __uint_as_float(u & 0xFFFF0000u);
  lo = (unsigned short)(__float_as_uint(r) >> 16);
}

// Fused 2-layer LSTM + FC. grid 256 (16-batch tiles), block 768 (12 waves).
// lstm2: waves 0-3 = owners (gates i,f + cell update) for cell-groups 0-3;
//        waves 4-7 = partners (gates g,o -> LDS).
// lstm1: wave 8 = owner (i + update), waves 9/10/11 = f/g/o; wave 10 also
//        stages x into an 8-deep LDS ring (reload once per 8 steps).
// 2 barriers per superstep; lstm1 runs one step ahead of lstm2.
__global__ __launch_bounds__(768) void lstm_fused_kernel(
    const float* __restrict__ x,
    const float* __restrict__ w_ih1, const float* __restrict__ w_hh1,
    const float* __restrict__ b_ih1, const float* __restrict__ b_hh1,
    const float* __restrict__ w_ih2, const float* __restrict__ w_hh2,
    const float* __restrict__ b_ih2, const float* __restrict__ b_hh2,
    const float* __restrict__ fc_w, const float* __restrict__ fc_b,
    float* __restrict__ out)
{
  const int tid  = threadIdx.x;
  const int lane = tid & 63;
  const int wave = tid >> 6;
  const int l15  = lane & 15;
  const int quad = lane >> 4;
  const int b0   = blockIdx.x * 16;

  // A2: [batch16][col72]: h2 0-49 | h1 50-54 | zero 55-71 (stride 144B = 16B-mult)
  __shared__ __align__(16) unsigned short a2h[16*72], a2l[16*72];
  // A1 h-part: [batch16][col24]: h1 0-4 | zero (only cols 0-15 read)
  __shared__ __align__(16) unsigned short a1h[16*24], a1l[16*24];
  // x ring: [slot8][batch16][col24]: x dims 0-15, pad (stride 48B)
  __shared__ __align__(16) unsigned short xrh[8*16*24], xrl[8*16*24];
  __shared__ float g2[2*16*68];   // lstm2 partner gates g,o: [t][row][cell(68)]
  __shared__ float g1[3*16*8 + 16]; // lstm1 gates f,g,o: [t][row][8] (+pad)
  __shared__ float h2f[16*52];

  // ---- weights / bias (registers, loop-invariant) ----
  bf16x8 Bh[2][2], Bl[2][2];
  float bias0 = 0.f, bias1 = 0.f;
  const bool is2  = wave < 8;
  const int  grp  = wave & 3;
  const int  role = wave >> 2;     // lstm2: 0=owner(i,f) 1=partner(g,o)
  const int  cg   = grp*16 + l15;  // lstm2 cell

  if (is2){
    bool valid = cg < H2;
#pragma unroll
    for (int tl=0; tl<2; ++tl){
      int tt = role*2 + tl;
      int grow = tt*H2 + cg;
#pragma unroll
      for (int kt=0; kt<2; ++kt){
#pragma unroll
        for (int j=0;j<8;j++){
          int kk = kt*32 + quad*8 + j;
          float w = 0.f;
          if (valid){
            if (kk < H2)         w = w_hh2[grow*H2 + kk];
            else if (kk < H2+H1) w = w_ih2[grow*H1 + (kk-H2)];
          }
          unsigned u = __float_as_uint(w);
          Bh[tl][kt][j] = (short)(u >> 16);
          float r = w - __uint_as_float(u & 0xFFFF0000u);
          Bl[tl][kt][j] = (short)(__float_as_uint(r) >> 16);
        }
      }
      float bv = valid ? (b_ih2[grow] + b_hh2[grow]) : 0.f;
      if (tl==0) bias0 = bv; else bias1 = bv;
    }
  } else {
    int tt = wave & 3;             // 8->0(i) 9->1(f) 10->2(g) 11->3(o)
    bool valid = l15 < H1;
    int grow = tt*H1 + l15;
#pragma unroll
    for (int j=0;j<8;j++){
      int kk = quad*8 + j;
      float w = 0.f;
      if (valid){
        if (kk < IN_DIM)             w = w_ih1[grow*IN_DIM + kk];
        else if (kk < IN_DIM+H1)     w = w_hh1[grow*H1 + (kk-IN_DIM)];
      }
      unsigned u = __float_as_uint(w);
      Bh[0][0][j] = (short)(u >> 16);
      float r = w - __uint_as_float(u & 0xFFFF0000u);
      Bl[0][0][j] = (short)(__float_as_uint(r) >> 16);
      Bh[0][1][j] = 0; Bl[0][1][j] = 0;
      Bh[1][0][j] = 0; Bl[1][0][j] = 0;
      Bh[1][1][j] = 0; Bl[1][1][j] = 0;
    }
    bias0 = valid ? (b_ih1[grow] + b_hh1[grow]) : 0.f;
  }

  // zero state LDS
  for (int i=tid;i<16*72;i+=768){ a2h[i]=0; a2l[i]=0; }
  for (int i=tid;i<16*24;i+=768){ a1h[i]=0; a1l[i]=0; }

  // preload x(0..7) into ring (wave 10)
  const int xb = lane >> 2;
  const int xd = (lane & 3) * 4;
  if (wave == 10){
#pragma unroll
    for (int s=0;s<8;s++){
      float4 v = *(const float4*)&x[((size_t)(b0+xb)*T_STEPS + s)*IN_DIM + xd];
      cvt_store(&xrh[(s*16+xb)*24+xd], &xrl[(s*16+xb)*24+xd], v);
    }
  }
  __syncthreads();

  float cst[4] = {0.f,0.f,0.f,0.f};
  float x7x=0.f, x7y=0.f, x7z=0.f, x7w=0.f;  // slot-7 carry across bar_mid

  for (int t=0; t<=T_STEPS; ++t){
    // ================= phase 1 =================
    f32x4 acc0 = {0,0,0,0}, acc1 = {0,0,0,0};
    bool reload = false;

    if (is2){
      if (t >= 1){
        const int rb = l15*72;
        bf16x8 ah0 = *(const bf16x8*)&a2h[rb +      quad*8];
        bf16x8 al0 = *(const bf16x8*)&a2l[rb +      quad*8];
        bf16x8 ah1 = *(const bf16x8*)&a2h[rb + 32 + quad*8];
        bf16x8 al1 = *(const bf16x8*)&a2l[rb + 32 + quad*8];
        acc0 = (f32x4){bias0,bias0,bias0,bias0};
        acc0 = __builtin_amdgcn_mfma_f32_16x16x32_bf16(ah0, Bh[0][0], acc0, 0,0,0);
        acc0 = __builtin_amdgcn_mfma_f32_16x16x32_bf16(al0, Bh[0][0], acc0, 0,0,0);
        acc0 = __builtin_amdgcn_mfma_f32_16x16x32_bf16(ah0, Bl[0][0], acc0, 0,0,0);
        acc0 = __builtin_amdgcn_mfma_f32_16x16x32_bf16(ah1, Bh[0][1], acc0, 0,0,0);
        acc0 = __builtin_amdgcn_mfma_f32_16x16x32_bf16(al1, Bh[0][1], acc0, 0,0,0);
        acc0 = __builtin_amdgcn_mfma_f32_16x16x32_bf16(ah1, Bl[0][1], acc0, 0,0,0);
        acc1 = (f32x4){bias1,bias1,bias1,bias1};
        acc1 = __builtin_amdgcn_mfma_f32_16x16x32_bf16(ah0, Bh[1][0], acc1, 0,0,0);
        acc1 = __builtin_amdgcn_mfma_f32_16x16x32_bf16(al0, Bh[1][0], acc1, 0,0,0);
        acc1 = __builtin_amdgcn_mfma_f32_16x16x32_bf16(ah0, Bl[1][0], acc1, 0,0,0);
        acc1 = __builtin_amdgcn_mfma_f32_16x16x32_bf16(ah1, Bh[1][1], acc1, 0,0,0);
        acc1 = __builtin_amdgcn_mfma_f32_16x16x32_bf16(al1, Bh[1][1], acc1, 0,0,0);
        acc1 = __builtin_amdgcn_mfma_f32_16x16x32_bf16(ah1, Bl[1][1], acc1, 0,0,0);
        if (role == 0){
          // own gates i,f -> activate now, keep in regs over bar_mid
#pragma unroll
          for (int r=0;r<4;r++){ acc0[r] = sigm(acc0[r]); acc1[r] = sigm(acc1[r]); }
        } else {
#pragma unroll
          for (int r=0;r<4;r++){
            float g = tanh_(acc0[r]);
            float o = sigm(acc1[r]);
            int row = quad*4 + r;
            g2[       row*68 + cg] = g;
            g2[1088 + row*68 + cg] = o;
          }
        }
      }
    } else {
      if (t < T_STEPS){
        // x ring reload (wave 10), covers x(t+1..t+8)
        float4 xv0,xv1,xv2,xv3,xv4,xv5,xv6,xv7;
        reload = (wave==10) && ((t & 7) == 7) && (t < T_STEPS-8);
        if (reload){
          const float* xp = &x[((size_t)(b0+xb)*T_STEPS + (t+1))*IN_DIM + xd];
          xv0 = *(const float4*)(xp +  0*IN_DIM);
          xv1 = *(const float4*)(xp +  1*IN_DIM);
          xv2 = *(const float4*)(xp +  2*IN_DIM);
          xv3 = *(const float4*)(xp +  3*IN_DIM);
          xv4 = *(const float4*)(xp +  4*IN_DIM);
          xv5 = *(const float4*)(xp +  5*IN_DIM);
          xv6 = *(const float4*)(xp +  6*IN_DIM);
          xv7 = *(const float4*)(xp +  7*IN_DIM);
        }
        // A-frag: quads 0-1 from x ring slot (t&7), quads 2-3 from a1
        const int slot = t & 7;
        const unsigned short* ph;
        const unsigned short* pl;
        if (quad < 2){
          int off = (slot*16 + l15)*24 + quad*8;
          ph = &xrh[off]; pl = &xrl[off];
        } else {
          int off = l15*24 + (quad-2)*8;
          ph = &a1h[off]; pl = &a1l[off];
        }
        bf16x8 ah = *(const bf16x8*)ph;
        bf16x8 al = *(const bf16x8*)pl;
        acc0 = (f32x4){bias0,bias0,bias0,bias0};
        acc0 = __builtin_amdgcn_mfma_f32_16x16x32_bf16(ah, Bh[0][0], acc0, 0,0,0);
        acc0 = __builtin_amdgcn_mfma_f32_16x16x32_bf16(al, Bh[0][0], acc0, 0,0,0);
        acc0 = __builtin_amdgcn_mfma_f32_16x16x32_bf16(ah, Bl[0][0], acc0, 0,0,0);
        int tt = wave & 3;
        if (wave == 8){
#pragma unroll
          for (int r=0;r<4;r++) acc0[r] = sigm(acc0[r]);
        } else {
#pragma unroll
          for (int r=0;r<4;r++){
            float v = (tt==2) ? tanh_(acc0[r]) : sigm(acc0[r]);
            if (l15 < 8) g1[(tt-1)*128 + (quad*4+r)*8 + l15] = v;
          }
        }
        // convert + store ring slots 0..6 (x(t+1..t+7)); keep slot 7 in regs
        if (reload){
          int base = ((t+1) & 7); (void)base; // == 0
          cvt_store(&xrh[(0*16+xb)*24+xd], &xrl[(0*16+xb)*24+xd], xv0);
          cvt_store(&xrh[(1*16+xb)*24+xd], &xrl[(1*16+xb)*24+xd], xv1);
          cvt_store(&xrh[(2*16+xb)*24+xd], &xrl[(2*16+xb)*24+xd], xv2);
          cvt_store(&xrh[(3*16+xb)*24+xd], &xrl[(3*16+xb)*24+xd], xv3);
          cvt_store(&xrh[(4*16+xb)*24+xd], &xrl[(4*16+xb)*24+xd], xv4);
          cvt_store(&xrh[(5*16+xb)*24+xd], &xrl[(5*16+xb)*24+xd], xv5);
          cvt_store(&xrh[(6*16+xb)*24+xd], &xrl[(6*16+xb)*24+xd], xv6);
          x7x = xv7.x; x7y = xv7.y; x7z = xv7.z; x7w = xv7.w;
        }
      }
    }

    __syncthreads();  // ---- bar_mid: gates visible; all A-frag reads done ----

    // ================= phase 2 =================
    if (is2){
      if (role == 0 && t >= 1){
        float gg[4], go[4];
#pragma unroll
        for (int r=0;r<4;r++){
          int row = quad*4 + r;
          gg[r] = g2[       row*68 + cg];
          go[r] = g2[1088 + row*68 + cg];
        }
#pragma unroll
        for (int r=0;r<4;r++){
          cst[r] = acc1[r]*cst[r] + acc0[r]*gg[r];
          float h = go[r] * tanh_(cst[r]);
          int row = quad*4 + r;
          if (cg < H2){
            unsigned short hh, hl;
            split1(h, hh, hl);
            a2h[row*72 + cg] = hh;
            a2l[row*72 + cg] = hl;
            if (t == T_STEPS){
              out[(size_t)B_TOTAL*NCLS + (size_t)(b0+row)*H2 + cg] = h;
              h2f[row*52 + cg] = h;
            }
          }
        }
      }
    } else if (t < T_STEPS){
      if (wave == 8){
        int cc = (l15 < H1) ? l15 : 0;
        float gf[4], gg[4], go[4];
#pragma unroll
        for (int r=0;r<4;r++){
          int row = quad*4 + r;
          gf[r] = g1[0*128 + row*8 + cc];
          gg[r] = g1[1*128 + row*8 + cc];
          go[r] = g1[2*128 + row*8 + cc];
        }
#pragma unroll
        for (int r=0;r<4;r++){
          cst[r] = gf[r]*cst[r] + acc0[r]*gg[r];
          float h = go[r] * tanh_(cst[r]);
          int row = quad*4 + r;
          if (l15 < H1){
            unsigned short hh, hl;
            split1(h, hh, hl);
            a1h[row*24 + cc] = hh;
            a1l[row*24 + cc] = hl;
            a2h[row*72 + H2 + cc] = hh;
            a2l[row*72 + H2 + cc] = hl;
          }
        }
      }
      if (reload){
        float4 v; v.x=x7x; v.y=x7y; v.z=x7z; v.w=x7w;
        cvt_store(&xrh[(7*16+xb)*24+xd], &xrl[(7*16+xb)*24+xd], v);
      }
    }

    __syncthreads();  // ---- bar_end: h(t) published ----
  }

  // fused FC: 16 batches x 20 outputs (h2f visible after bar_end of t=512)
  if (tid < 320){
    int b = tid / 20, o = tid % 20;
    float s = fc_b[o];
#pragma unroll 10
    for (int k=0;k<H2;k++) s += fc_w[o*H2+k] * h2f[b*52+k];
    out[(size_t)(b0+b)*NCLS + o] = s;
  }
}

extern "C" void kernel_launch(void* const* d_in, const int* in_sizes, int n_in,
                              void* d_out, int out_size, void* d_ws, size_t ws_size,
                              hipStream_t stream) {
  const float* x     = (const float*)d_in[0];
  const float* w_ih1 = (const float*)d_in[1];
  const float* w_hh1 = (const float*)d_in[2];
  const float* b_ih1 = (const float*)d_in[3];
  const float* b_hh1 = (const float*)d_in[4];
  const float* w_ih2 = (const float*)d_in[5];
  const float* w_hh2 = (const float*)d_in[6];
  const float* b_ih2 = (const float*)d_in[7];
  const float* b_hh2 = (const float*)d_in[8];
  const float* fc_w  = (const float*)d_in[9];
  const float* fc_b  = (const float*)d_in[10];
  float* out = (float*)d_out;

  lstm_fused_kernel<<<dim3(B_TOTAL/16), dim3(768), 0, stream>>>(
      x, w_ih1, w_hh1, b_ih1, b_hh1, w_ih2, w_hh2, b_ih2, b_hh2, fc_w, fc_b, out);
}